// Round 1
// baseline (1179.736 us; speedup 1.0000x reference)
//
#include <hip/hip_runtime.h>
#include <hip/hip_bf16.h>
#include <math.h>

#define T_DIM 1024
#define B_DIM 8
#define D_DIM 1024
#define H_DIM 16
#define DH 64
#define M_ROWS 8192          // T*B
#define N_COLS 5120          // 5*D
#define K_DIM 1024

typedef __attribute__((ext_vector_type(8))) short short8;
typedef __attribute__((ext_vector_type(4))) float floatx4;

static __device__ __forceinline__ unsigned short f2bf(float f){
    unsigned int u = __float_as_uint(f);
    u += 0x7fff + ((u >> 16) & 1);          // RNE
    return (unsigned short)(u >> 16);
}

static __device__ __forceinline__ float sigf(float x){
    return 1.f / (1.f + __expf(-x));
}

// ---------------- fp32 -> bf16 conversion (vectorized) ----------------
__global__ void cvt_bf16(const float* __restrict__ src, unsigned short* __restrict__ dst, int n4){
    int i = blockIdx.x*blockDim.x + threadIdx.x;
    int stride = gridDim.x*blockDim.x;
    for (; i < n4; i += stride){
        float4 f = ((const float4*)src)[i];
        ushort4 o;
        o.x = f2bf(f.x); o.y = f2bf(f.y); o.z = f2bf(f.z); o.w = f2bf(f.w);
        ((ushort4*)dst)[i] = o;
    }
}

// ---------------- NT GEMM: C[m,n] = sum_k A[m,k]*B[n,k] ----------------
// A: 8192x1024 bf16, B: 5120x1024 bf16, C: 8192x5120 fp32
#define GLD16(g, l) __builtin_amdgcn_global_load_lds(                         \
    (const __attribute__((address_space(1))) void*)(g),                       \
    (__attribute__((address_space(3))) void*)(l), 16, 0, 0)

__global__ __launch_bounds__(256) void gemm_bt(const unsigned short* __restrict__ A,
                                               const unsigned short* __restrict__ B,
                                               float* __restrict__ C){
    __shared__ unsigned short As[128*32];
    __shared__ unsigned short Bs[128*32];
    const int tid = threadIdx.x;
    const int rowBase = blockIdx.y * 128;
    const int colBase = blockIdx.x * 128;
    const int l  = tid & 63;
    const int wv = tid >> 6;
    const int wm = (wv >> 1) * 64;   // wave m-offset in tile
    const int wn = (wv & 1) * 64;    // wave n-offset in tile

    floatx4 acc[4][4] = {};

    const int r0 = tid >> 2;          // 0..63
    const int kj = (tid & 3) * 8;     // 0,8,16,24
    const unsigned short* gA0 = A + (size_t)(rowBase + r0)      * K_DIM + kj;
    const unsigned short* gA1 = A + (size_t)(rowBase + r0 + 64) * K_DIM + kj;
    const unsigned short* gB0 = B + (size_t)(colBase + r0)      * K_DIM + kj;
    const unsigned short* gB1 = B + (size_t)(colBase + r0 + 64) * K_DIM + kj;
    unsigned short* lA0 = &As[tid*8];
    unsigned short* lA1 = &As[(tid+256)*8];
    unsigned short* lB0 = &Bs[tid*8];
    unsigned short* lB1 = &Bs[(tid+256)*8];

    const int fr = l & 15;            // fragment row within 16
    const int fk = (l >> 4) * 8;      // fragment k offset (0,8,16,24)

    for (int kc = 0; kc < K_DIM; kc += 32){
        __syncthreads();
        GLD16(gA0 + kc, lA0);
        GLD16(gA1 + kc, lA1);
        GLD16(gB0 + kc, lB0);
        GLD16(gB1 + kc, lB1);
        __syncthreads();
        short8 af[4], bfr[4];
        #pragma unroll
        for (int i = 0; i < 4; i++)
            af[i] = *(const short8*)&As[(wm + i*16 + fr)*32 + fk];
        #pragma unroll
        for (int j = 0; j < 4; j++)
            bfr[j] = *(const short8*)&Bs[(wn + j*16 + fr)*32 + fk];
        #pragma unroll
        for (int i = 0; i < 4; i++)
            #pragma unroll
            for (int j = 0; j < 4; j++)
                acc[i][j] = __builtin_amdgcn_mfma_f32_16x16x32_bf16(af[i], bfr[j], acc[i][j], 0, 0, 0);
    }

    // epilogue: lane l, reg r -> row = (l>>4)*4 + r, col = l&15   [m89/m91 layout]
    const int crow0 = rowBase + wm + (l >> 4) * 4;
    const int ccol0 = colBase + wn + (l & 15);
    #pragma unroll
    for (int i = 0; i < 4; i++)
        #pragma unroll
        for (int j = 0; j < 4; j++)
            #pragma unroll
            for (int r = 0; r < 4; r++)
                C[(size_t)(crow0 + i*16 + r) * N_COLS + (ccol0 + j*16)] = acc[i][j][r];
}

// ---------------- post-pass: inv-norms for q/k, sigmoid-means for alpha/beta ----
// one block per row i; thread = h*16 + j, j covers 4 elements
__global__ __launch_bounds__(256) void postpass(const float* __restrict__ C,
        const float* __restrict__ b_alpha, const float* __restrict__ b_beta,
        float* __restrict__ qn, float* __restrict__ kn,
        float* __restrict__ al, float* __restrict__ bt){
    const int i = blockIdx.x;
    const int tid = threadIdx.x;
    const int h = tid >> 4;
    const int j = tid & 15;
    const int e = j * 4;
    const float* base = C + (size_t)i * N_COLS;

    float4 q4 = *(const float4*)(base +        h*64 + e);
    float4 k4 = *(const float4*)(base + 1024 + h*64 + e);
    float4 a4 = *(const float4*)(base + 3072 + h*64 + e);
    float4 b4 = *(const float4*)(base + 4096 + h*64 + e);
    float4 ba = *(const float4*)(b_alpha + h*64 + e);
    float4 bb = *(const float4*)(b_beta  + h*64 + e);

    float qs = q4.x*q4.x + q4.y*q4.y + q4.z*q4.z + q4.w*q4.w;
    float ks = k4.x*k4.x + k4.y*k4.y + k4.z*k4.z + k4.w*k4.w;
    float as_ = sigf(a4.x+ba.x) + sigf(a4.y+ba.y) + sigf(a4.z+ba.z) + sigf(a4.w+ba.w);
    float bs_ = sigf(b4.x+bb.x) + sigf(b4.y+bb.y) + sigf(b4.z+bb.z) + sigf(b4.w+bb.w);

    #pragma unroll
    for (int off = 1; off < 16; off <<= 1){
        qs  += __shfl_xor(qs,  off);
        ks  += __shfl_xor(ks,  off);
        as_ += __shfl_xor(as_, off);
        bs_ += __shfl_xor(bs_, off);
    }
    if (j == 0){
        qn[i*16 + h] = 1.f / fmaxf(sqrtf(qs), 1e-12f);
        kn[i*16 + h] = 1.f / fmaxf(sqrtf(ks), 1e-12f);
        al[i*16 + h] = as_ * (1.f/64.f);
        bt[i*16 + h] = bs_ * (1.f/64.f);
    }
}

// ---------------- sequential scan over T ----------------
// 256 blocks: blockIdx.x = bh*2 + half; block owns 32 rows of S[b,h]
// thread: lr = tid>>3 (row within half), j = tid&7 (8 state cols each)
__global__ __launch_bounds__(256) void scan_kernel(const float* __restrict__ C,
        const float* __restrict__ qn, const float* __restrict__ kn,
        const float* __restrict__ al, const float* __restrict__ bt,
        const float* __restrict__ S0, float* __restrict__ out){
    const int bh   = blockIdx.x >> 1;
    const int half = blockIdx.x & 1;
    const int b = bh >> 4;
    const int h = bh & 15;
    const int tid = threadIdx.x;
    const int lr = tid >> 3;
    const int j  = tid & 7;
    const int d  = half*32 + lr;

    __shared__ float kb[64], qb[64], vb[64];
    __shared__ float sAB[2];

    float s[8];
    const float* s0p = S0 + ((size_t)(b*16 + h)*64 + d)*64 + j*8;
    #pragma unroll
    for (int e = 0; e < 8; e++) s[e] = s0p[e];

    for (int t = 0; t < T_DIM; t++){
        const int i = t*8 + b;
        const float* rowp = C + (size_t)i * N_COLS + h*64;
        if (tid < 64){
            kb[tid] = rowp[1024 + tid] * kn[i*16 + h];
        } else if (tid < 128){
            int e2 = tid - 64;
            qb[e2] = rowp[e2] * qn[i*16 + h];
        } else if (tid < 192){
            int e2 = tid - 128;
            vb[e2] = rowp[2048 + e2];
        } else if (tid == 192){
            sAB[0] = al[i*16 + h];
        } else if (tid == 193){
            sAB[1] = bt[i*16 + h];
        }
        __syncthreads();

        const float a  = sAB[0];
        const float be = sAB[1];
        float kk[8];
        float sk = 0.f;
        #pragma unroll
        for (int e = 0; e < 8; e++){ kk[e] = kb[j*8 + e]; sk += s[e]*kk[e]; }
        sk += __shfl_xor(sk, 1);
        sk += __shfl_xor(sk, 2);
        sk += __shfl_xor(sk, 4);

        const float c1 = be * (vb[d] - a * sk);
        float o = 0.f;
        #pragma unroll
        for (int e = 0; e < 8; e++){
            s[e] = a*s[e] + c1*kk[e];
            o += s[e] * qb[j*8 + e];
        }
        o += __shfl_xor(o, 1);
        o += __shfl_xor(o, 2);
        o += __shfl_xor(o, 4);
        if (j == 0) out[(size_t)t*8192 + b*1024 + h*64 + d] = o;
        __syncthreads();
    }

    // S_final
    float* sf = out + (size_t)8388608 + ((size_t)(b*16 + h)*64 + d)*64 + j*8;
    #pragma unroll
    for (int e = 0; e < 8; e++) sf[e] = s[e];
}

extern "C" void kernel_launch(void* const* d_in, const int* in_sizes, int n_in,
                              void* d_out, int out_size, void* d_ws, size_t ws_size,
                              hipStream_t stream){
    const float* x  = (const float*)d_in[0];
    const float* S0 = (const float*)d_in[1];
    const float* Wq = (const float*)d_in[2];
    const float* Wk = (const float*)d_in[3];
    const float* Wv = (const float*)d_in[4];
    const float* Wa = (const float*)d_in[5];
    const float* ba = (const float*)d_in[6];
    const float* Wb = (const float*)d_in[7];
    const float* bb = (const float*)d_in[8];
    float* out = (float*)d_out;

    char* ws = (char*)d_ws;
    unsigned short* Abf = (unsigned short*)ws;                    // 16,777,216 B
    unsigned short* Bbf = (unsigned short*)(ws + 16777216);       // 10,485,760 B
    float* Cm = (float*)(ws + 27262976);                          // 167,772,160 B
    float* qn = (float*)(ws + 195035136);                         //    524,288 B
    float* kn = (float*)(ws + 195559424);
    float* al = (float*)(ws + 196083712);
    float* bt = (float*)(ws + 196608000);                         // end 197,132,288

    // conversions
    cvt_bf16<<<1024, 256, 0, stream>>>(x, Abf, (M_ROWS*K_DIM)/4);
    const int nW4 = (1024*1024)/4;
    cvt_bf16<<<256, 256, 0, stream>>>(Wq, Bbf + 0*1024*1024, nW4);
    cvt_bf16<<<256, 256, 0, stream>>>(Wk, Bbf + 1*1024*1024, nW4);
    cvt_bf16<<<256, 256, 0, stream>>>(Wv, Bbf + 2*1024*1024, nW4);
    cvt_bf16<<<256, 256, 0, stream>>>(Wa, Bbf + 3*1024*1024, nW4);
    cvt_bf16<<<256, 256, 0, stream>>>(Wb, Bbf + 4*1024*1024, nW4);

    // fused projection GEMM
    dim3 gg(N_COLS/128, M_ROWS/128);   // 40 x 64
    gemm_bt<<<gg, 256, 0, stream>>>(Abf, Bbf, Cm);

    // norms + gates
    postpass<<<M_ROWS, 256, 0, stream>>>(Cm, ba, bb, qn, kn, al, bt);

    // recurrence
    scan_kernel<<<256, 256, 0, stream>>>(Cm, qn, kn, al, bt, S0, out);
}

// Round 2
// 481.646 us; speedup vs baseline: 2.4494x; 2.4494x over previous
//
#include <hip/hip_runtime.h>
#include <hip/hip_bf16.h>
#include <math.h>

#define T_DIM 1024
#define B_DIM 8
#define D_DIM 1024
#define H_DIM 16
#define DH 64
#define M_ROWS 8192          // T*B
#define N_COLS 5120          // 5*D
#define NP_COLS 3072         // q,k,v only materialized
#define K_DIM 1024
#define CT 32                // scan chunk (timesteps per LDS stage)
#define NCHUNK (T_DIM / CT)

typedef __attribute__((ext_vector_type(8))) short short8;
typedef __attribute__((ext_vector_type(4))) float floatx4;

static __device__ __forceinline__ unsigned short f2bf(float f){
    unsigned int u = __float_as_uint(f);
    u += 0x7fff + ((u >> 16) & 1);          // RNE
    return (unsigned short)(u >> 16);
}
static __device__ __forceinline__ float sigf(float x){
    return 1.f / (1.f + __expf(-x));
}
static __device__ __forceinline__ float bflo(unsigned int w){ return __uint_as_float(w << 16); }
static __device__ __forceinline__ float bfhi(unsigned int w){ return __uint_as_float(w & 0xffff0000u); }

// DPP butterfly adds (VALU pipe, not DS): xor1=quad_perm[1,0,3,2]=0xB1,
// xor2=quad_perm[2,3,0,1]=0x4E, xor4=row_half_mirror=0x141, xor8=row_mirror=0x140
#define DPPADD(x, ctrl) ((x) + __int_as_float(__builtin_amdgcn_update_dpp(0, __float_as_int(x), (ctrl), 0xF, 0xF, true)))
static __device__ __forceinline__ float red8(float x){
    x = DPPADD(x, 0xB1); x = DPPADD(x, 0x4E); x = DPPADD(x, 0x141); return x;
}
static __device__ __forceinline__ float red16(float x){
    x = red8(x); x = DPPADD(x, 0x140); return x;
}

// ---------------- fp32 -> bf16 conversion ----------------
__global__ void cvt_bf16(const float* __restrict__ src, unsigned short* __restrict__ dst, int n4){
    int i = blockIdx.x*blockDim.x + threadIdx.x;
    int stride = gridDim.x*blockDim.x;
    for (; i < n4; i += stride){
        float4 f = ((const float4*)src)[i];
        ushort4 o;
        o.x = f2bf(f.x); o.y = f2bf(f.y); o.z = f2bf(f.z); o.w = f2bf(f.w);
        ((ushort4*)dst)[i] = o;
    }
}

// all 5 weight matrices in one launch; each is 1024x1024 fp32
__global__ void cvt_w(const float* __restrict__ w0, const float* __restrict__ w1,
                      const float* __restrict__ w2, const float* __restrict__ w3,
                      const float* __restrict__ w4, unsigned short* __restrict__ dst){
    int i = blockIdx.x*blockDim.x + threadIdx.x;   // one float4 each; 5*262144 total
    int seg = i >> 18;
    int off = i & 262143;
    const float* src = (seg==0)?w0:(seg==1)?w1:(seg==2)?w2:(seg==3)?w3:w4;
    float4 f = ((const float4*)src)[off];
    ushort4 o;
    o.x = f2bf(f.x); o.y = f2bf(f.y); o.z = f2bf(f.z); o.w = f2bf(f.w);
    ((ushort4*)dst)[i] = o;
}

// ---------------- NT GEMM + fused gate epilogue ----------------
// A: 8192x1024 bf16, B: 5120x1024 bf16.
// n-tile < 24: store q/k/v fp32 to C (stride 3072)
// n-tile 24..31: alpha gates -> G[rec][0];  32..39: beta -> G[rec][1]
#define GLD16(g, l) __builtin_amdgcn_global_load_lds(                         \
    (const __attribute__((address_space(1))) void*)(g),                       \
    (__attribute__((address_space(3))) void*)(l), 16, 0, 0)
#define GLD4(g, l) __builtin_amdgcn_global_load_lds(                          \
    (const __attribute__((address_space(1))) void*)(g),                       \
    (__attribute__((address_space(3))) void*)(l), 4, 0, 0)

__global__ __launch_bounds__(256) void gemm_bt(const unsigned short* __restrict__ A,
                                               const unsigned short* __restrict__ B,
                                               float* __restrict__ C,
                                               float* __restrict__ G,
                                               const float* __restrict__ b_alpha,
                                               const float* __restrict__ b_beta){
    __shared__ unsigned short As[128*32];
    __shared__ unsigned short Bs[128*32];
    const int tid = threadIdx.x;
    const int rowBase = blockIdx.y * 128;
    const int colBase = blockIdx.x * 128;
    const int l  = tid & 63;
    const int wv = tid >> 6;
    const int wm = (wv >> 1) * 64;
    const int wn = (wv & 1) * 64;

    floatx4 acc[4][4] = {};

    const int r0 = tid >> 2;
    const int kj = (tid & 3) * 8;
    const unsigned short* gA0 = A + (size_t)(rowBase + r0)      * K_DIM + kj;
    const unsigned short* gA1 = A + (size_t)(rowBase + r0 + 64) * K_DIM + kj;
    const unsigned short* gB0 = B + (size_t)(colBase + r0)      * K_DIM + kj;
    const unsigned short* gB1 = B + (size_t)(colBase + r0 + 64) * K_DIM + kj;
    unsigned short* lA0 = &As[tid*8];
    unsigned short* lA1 = &As[(tid+256)*8];
    unsigned short* lB0 = &Bs[tid*8];
    unsigned short* lB1 = &Bs[(tid+256)*8];

    const int fr = l & 15;
    const int fk = (l >> 4) * 8;

    for (int kc = 0; kc < K_DIM; kc += 32){
        __syncthreads();
        GLD16(gA0 + kc, lA0);
        GLD16(gA1 + kc, lA1);
        GLD16(gB0 + kc, lB0);
        GLD16(gB1 + kc, lB1);
        __syncthreads();
        short8 af[4], bfr[4];
        #pragma unroll
        for (int i = 0; i < 4; i++)
            af[i] = *(const short8*)&As[(wm + i*16 + fr)*32 + fk];
        #pragma unroll
        for (int jj = 0; jj < 4; jj++)
            bfr[jj] = *(const short8*)&Bs[(wn + jj*16 + fr)*32 + fk];
        #pragma unroll
        for (int i = 0; i < 4; i++)
            #pragma unroll
            for (int jj = 0; jj < 4; jj++)
                acc[i][jj] = __builtin_amdgcn_mfma_f32_16x16x32_bf16(af[i], bfr[jj], acc[i][jj], 0, 0, 0);
    }

    const int ntile = blockIdx.x;
    if (ntile < 24){
        // q/k/v: store fp32 at stride NP_COLS
        const int crow0 = rowBase + wm + (l >> 4) * 4;
        const int ccol0 = colBase + wn + (l & 15);
        #pragma unroll
        for (int i = 0; i < 4; i++)
            #pragma unroll
            for (int jj = 0; jj < 4; jj++)
                #pragma unroll
                for (int r = 0; r < 4; r++)
                    C[(size_t)(crow0 + i*16 + r) * NP_COLS + (ccol0 + jj*16)] = acc[i][jj][r];
    } else {
        // gate tiles: sigmoid + mean over head dim (64 cols = this wave's col range)
        const int isBeta = (ntile >= 32) ? 1 : 0;
        const float* bias = isBeta ? b_beta : b_alpha;
        const int gcol0 = colBase + wn - (isBeta ? 4096 : 3072);   // 0..960
        const int hh = gcol0 >> 6;                                  // head 0..15
        float bj[4];
        #pragma unroll
        for (int jj = 0; jj < 4; jj++) bj[jj] = bias[gcol0 + jj*16 + (l & 15)];
        #pragma unroll
        for (int i = 0; i < 4; i++){
            #pragma unroll
            for (int r = 0; r < 4; r++){
                float sum = 0.f;
                #pragma unroll
                for (int jj = 0; jj < 4; jj++) sum += sigf(acc[i][jj][r] + bj[jj]);
                sum = red16(sum);
                if ((l & 15) == 0){
                    const int row = rowBase + wm + i*16 + (l >> 4)*4 + r;
                    const int t = row >> 3, bb = row & 7;
                    G[((size_t)(bb*16 + hh)*1024 + t)*2 + isBeta] = sum * (1.f/64.f);
                }
            }
        }
    }
}

// ---------------- postpass: normalize q/k, pack scan stream ----------------
// KQV record per (bh, t): 512 B = [64 bf16 khat][64 bf16 qhat][64 fp32 v]
__global__ __launch_bounds__(256) void postpass(const float* __restrict__ C,
                                                unsigned char* __restrict__ KQV){
    const int i = blockIdx.x;           // row 0..8191; t=i>>3, b=i&7
    const int tid = threadIdx.x;
    const int h = tid >> 4;
    const int j = tid & 15;
    const int e = j * 4;
    const float* base = C + (size_t)i * NP_COLS;

    float4 q4 = *(const float4*)(base +        h*64 + e);
    float4 k4 = *(const float4*)(base + 1024 + h*64 + e);
    float4 v4 = *(const float4*)(base + 2048 + h*64 + e);

    float qs = q4.x*q4.x + q4.y*q4.y + q4.z*q4.z + q4.w*q4.w;
    float ks = k4.x*k4.x + k4.y*k4.y + k4.z*k4.z + k4.w*k4.w;
    qs = red16(qs);
    ks = red16(ks);
    const float rq = 1.f / fmaxf(sqrtf(qs), 1e-12f);
    const float rk = 1.f / fmaxf(sqrtf(ks), 1e-12f);

    const size_t rec = (size_t)((i & 7)*16 + h) * 1024 + (i >> 3);
    unsigned char* rp = KQV + rec * 512;
    ushort4 kp, qp;
    kp.x = f2bf(k4.x*rk); kp.y = f2bf(k4.y*rk); kp.z = f2bf(k4.z*rk); kp.w = f2bf(k4.w*rk);
    qp.x = f2bf(q4.x*rq); qp.y = f2bf(q4.y*rq); qp.z = f2bf(q4.z*rq); qp.w = f2bf(q4.w*rq);
    ((ushort4*)rp)[j]             = kp;          // bytes [0,128)
    ((ushort4*)(rp + 128))[j]     = qp;          // bytes [128,256)
    ((float4*)(rp + 256))[j]      = v4;          // bytes [256,512)
}

// ---------------- sequential scan ----------------
// 256 blocks: bh*2+half; 32 rows/block, 8 lanes x 8 state elems per row.
// Chunked double-buffered LDS staging, DPP reductions, no per-step barrier.
__global__ __launch_bounds__(256) void scan_kernel(const unsigned char* __restrict__ KQV,
        const float* __restrict__ G,
        const float* __restrict__ S0, float* __restrict__ out){
    const int bh   = blockIdx.x >> 1;
    const int half = blockIdx.x & 1;
    const int b = bh >> 4;
    const int h = bh & 15;
    const int tid = threadIdx.x;
    const int j  = tid & 7;
    const int lr = tid >> 3;            // 0..31
    const int d  = half*32 + lr;
    const int wv = tid >> 6;
    const int lane = tid & 63;

    __shared__ unsigned char sRec[2][CT*512];
    __shared__ float sG[2][CT*2];

    const unsigned char* gRec = KQV + (size_t)bh * (1024*512);
    const unsigned char* gG   = (const unsigned char*)G + (size_t)bh * (1024*8);

    // stage chunk 0
    {
        const unsigned char* src = gRec + wv*4096 + lane*16;
        unsigned char* dst = &sRec[0][0] + wv*4096 + lane*16;
        #pragma unroll
        for (int it = 0; it < 4; it++) GLD16(src + it*1024, dst + it*1024);
        if (wv == 0) GLD4(gG + lane*4, (unsigned char*)&sG[0][0] + lane*4);
    }

    float s[8];
    {
        const float* s0p = S0 + ((size_t)bh*64 + d)*64 + j*8;
        #pragma unroll
        for (int e2 = 0; e2 < 8; e2++) s[e2] = s0p[e2];
    }

    for (int c = 0; c < NCHUNK; ++c){
        __syncthreads();                        // chunk c ready (barrier drains vmcnt)
        const int buf = c & 1;
        if (c + 1 < NCHUNK){                    // prefetch chunk c+1 into other buffer
            const unsigned char* src = gRec + (size_t)(c+1)*(CT*512) + wv*4096 + lane*16;
            unsigned char* dst = &sRec[buf^1][0] + wv*4096 + lane*16;
            #pragma unroll
            for (int it = 0; it < 4; it++) GLD16(src + it*1024, dst + it*1024);
            if (wv == 0) GLD4(gG + (size_t)(c+1)*(CT*8) + lane*4,
                              (unsigned char*)&sG[buf^1][0] + lane*4);
        }
        #pragma unroll
        for (int tl = 0; tl < CT; ++tl){
            const unsigned char* rec = &sRec[buf][tl*512];
            const uint4 kw = *(const uint4*)(rec + (j<<4));
            const uint4 qw = *(const uint4*)(rec + 128 + (j<<4));
            const float vd = *(const float*)(rec + 256 + (d<<2));
            const float2 g = *(const float2*)(&sG[buf][tl*2]);

            float kk[8];
            kk[0]=bflo(kw.x); kk[1]=bfhi(kw.x); kk[2]=bflo(kw.y); kk[3]=bfhi(kw.y);
            kk[4]=bflo(kw.z); kk[5]=bfhi(kw.z); kk[6]=bflo(kw.w); kk[7]=bfhi(kw.w);

            float a0 = s[0]*kk[0] + s[4]*kk[4];
            float a1 = s[1]*kk[1] + s[5]*kk[5];
            float a2 = s[2]*kk[2] + s[6]*kk[6];
            float a3 = s[3]*kk[3] + s[7]*kk[7];
            float sk = (a0 + a1) + (a2 + a3);
            sk = red8(sk);

            const float c1 = g.y * (vd - g.x * sk);
            #pragma unroll
            for (int e2 = 0; e2 < 8; e2++) s[e2] = g.x*s[e2] + c1*kk[e2];

            float qq[8];
            qq[0]=bflo(qw.x); qq[1]=bfhi(qw.x); qq[2]=bflo(qw.y); qq[3]=bfhi(qw.y);
            qq[4]=bflo(qw.z); qq[5]=bfhi(qw.z); qq[6]=bflo(qw.w); qq[7]=bfhi(qw.w);
            float o0 = s[0]*qq[0] + s[4]*qq[4];
            float o1 = s[1]*qq[1] + s[5]*qq[5];
            float o2 = s[2]*qq[2] + s[6]*qq[6];
            float o3 = s[3]*qq[3] + s[7]*qq[7];
            float o = (o0 + o1) + (o2 + o3);
            o = red8(o);

            if (j == 0){
                const int t = c*CT + tl;
                out[(size_t)t*8192 + b*1024 + h*64 + d] = o;
            }
        }
    }

    // S_final
    float* sf = out + (size_t)8388608 + ((size_t)bh*64 + d)*64 + j*8;
    #pragma unroll
    for (int e2 = 0; e2 < 8; e2++) sf[e2] = s[e2];
}

extern "C" void kernel_launch(void* const* d_in, const int* in_sizes, int n_in,
                              void* d_out, int out_size, void* d_ws, size_t ws_size,
                              hipStream_t stream){
    const float* x  = (const float*)d_in[0];
    const float* S0 = (const float*)d_in[1];
    const float* Wq = (const float*)d_in[2];
    const float* Wk = (const float*)d_in[3];
    const float* Wv = (const float*)d_in[4];
    const float* Wa = (const float*)d_in[5];
    const float* ba = (const float*)d_in[6];
    const float* Wb = (const float*)d_in[7];
    const float* bb = (const float*)d_in[8];
    float* out = (float*)d_out;

    char* ws = (char*)d_ws;
    unsigned short* Abf = (unsigned short*)ws;                    // 16,777,216 B
    unsigned short* Bbf = (unsigned short*)(ws + 16777216);       // 10,485,760 B
    float* Cm  = (float*)(ws + 27262976);                         // 100,663,296 B (8192x3072 fp32)
    unsigned char* KQV = (unsigned char*)(ws + 127926272);        // 67,108,864 B (128*1024*512)
    float* G   = (float*)(ws + 195035136);                        //  1,048,576 B -> end 196,083,712

    // conversions
    cvt_bf16<<<2048, 256, 0, stream>>>(x, Abf, (M_ROWS*K_DIM)/4);
    cvt_w<<<5120, 256, 0, stream>>>(Wq, Wk, Wv, Wa, Wb, Bbf);

    // fused projection GEMM (q/k/v -> Cm; alpha/beta -> G)
    dim3 gg(N_COLS/128, M_ROWS/128);   // 40 x 64
    gemm_bt<<<gg, 256, 0, stream>>>(Abf, Bbf, Cm, G, ba, bb);

    // normalize + pack scan stream
    postpass<<<M_ROWS, 256, 0, stream>>>(Cm, KQV);

    // recurrence
    scan_kernel<<<256, 256, 0, stream>>>(KQV, G, S0, out);
}

// Round 3
// 449.808 us; speedup vs baseline: 2.6228x; 1.0708x over previous
//
#include <hip/hip_runtime.h>
#include <hip/hip_bf16.h>
#include <math.h>

#define T_DIM 1024
#define B_DIM 8
#define D_DIM 1024
#define H_DIM 16
#define DH 64
#define M_ROWS 8192          // T*B
#define N_COLS 5120          // 5*D
#define NP_COLS 3072         // q,k,v only materialized
#define K_DIM 1024
#define CT 32                // scan chunk (timesteps per LDS stage)
#define NCHUNK (T_DIM / CT)

typedef __attribute__((ext_vector_type(8))) short short8;
typedef __attribute__((ext_vector_type(4))) float floatx4;

static __device__ __forceinline__ unsigned short f2bf(float f){
    unsigned int u = __float_as_uint(f);
    u += 0x7fff + ((u >> 16) & 1);          // RNE
    return (unsigned short)(u >> 16);
}
static __device__ __forceinline__ float sigf(float x){
    return 1.f / (1.f + __expf(-x));
}
static __device__ __forceinline__ float bflo(unsigned int w){ return __uint_as_float(w << 16); }
static __device__ __forceinline__ float bfhi(unsigned int w){ return __uint_as_float(w & 0xffff0000u); }

// DPP butterfly adds (VALU pipe, not DS): xor1=quad_perm[1,0,3,2]=0xB1,
// xor2=quad_perm[2,3,0,1]=0x4E, xor4=row_half_mirror=0x141, xor8=row_mirror=0x140
#define DPPADD(x, ctrl) ((x) + __int_as_float(__builtin_amdgcn_update_dpp(0, __float_as_int(x), (ctrl), 0xF, 0xF, true)))
static __device__ __forceinline__ float red16(float x){
    x = DPPADD(x, 0xB1); x = DPPADD(x, 0x4E); x = DPPADD(x, 0x141); x = DPPADD(x, 0x140); return x;
}

// ---------------- fp32 -> bf16 conversion ----------------
__global__ void cvt_bf16(const float* __restrict__ src, unsigned short* __restrict__ dst, int n4){
    int i = blockIdx.x*blockDim.x + threadIdx.x;
    int stride = gridDim.x*blockDim.x;
    for (; i < n4; i += stride){
        float4 f = ((const float4*)src)[i];
        ushort4 o;
        o.x = f2bf(f.x); o.y = f2bf(f.y); o.z = f2bf(f.z); o.w = f2bf(f.w);
        ((ushort4*)dst)[i] = o;
    }
}

// all 5 weight matrices in one launch; each is 1024x1024 fp32
__global__ void cvt_w(const float* __restrict__ w0, const float* __restrict__ w1,
                      const float* __restrict__ w2, const float* __restrict__ w3,
                      const float* __restrict__ w4, unsigned short* __restrict__ dst){
    int i = blockIdx.x*blockDim.x + threadIdx.x;   // one float4 each; 5*262144 total
    int seg = i >> 18;
    int off = i & 262143;
    const float* src = (seg==0)?w0:(seg==1)?w1:(seg==2)?w2:(seg==3)?w3:w4;
    float4 f = ((const float4*)src)[off];
    ushort4 o;
    o.x = f2bf(f.x); o.y = f2bf(f.y); o.z = f2bf(f.z); o.w = f2bf(f.w);
    ((ushort4*)dst)[i] = o;
}

// ---------------- NT GEMM + fused gate epilogue ----------------
#define GLD16(g, l) __builtin_amdgcn_global_load_lds(                         \
    (const __attribute__((address_space(1))) void*)(g),                       \
    (__attribute__((address_space(3))) void*)(l), 16, 0, 0)
#define GLD4(g, l) __builtin_amdgcn_global_load_lds(                          \
    (const __attribute__((address_space(1))) void*)(g),                       \
    (__attribute__((address_space(3))) void*)(l), 4, 0, 0)

__global__ __launch_bounds__(256) void gemm_bt(const unsigned short* __restrict__ A,
                                               const unsigned short* __restrict__ B,
                                               float* __restrict__ C,
                                               float* __restrict__ G,
                                               const float* __restrict__ b_alpha,
                                               const float* __restrict__ b_beta){
    __shared__ unsigned short As[128*32];
    __shared__ unsigned short Bs[128*32];
    const int tid = threadIdx.x;
    const int rowBase = blockIdx.y * 128;
    const int colBase = blockIdx.x * 128;
    const int l  = tid & 63;
    const int wv = tid >> 6;
    const int wm = (wv >> 1) * 64;
    const int wn = (wv & 1) * 64;

    floatx4 acc[4][4] = {};

    const int r0 = tid >> 2;
    const int kj = (tid & 3) * 8;
    const unsigned short* gA0 = A + (size_t)(rowBase + r0)      * K_DIM + kj;
    const unsigned short* gA1 = A + (size_t)(rowBase + r0 + 64) * K_DIM + kj;
    const unsigned short* gB0 = B + (size_t)(colBase + r0)      * K_DIM + kj;
    const unsigned short* gB1 = B + (size_t)(colBase + r0 + 64) * K_DIM + kj;
    unsigned short* lA0 = &As[tid*8];
    unsigned short* lA1 = &As[(tid+256)*8];
    unsigned short* lB0 = &Bs[tid*8];
    unsigned short* lB1 = &Bs[(tid+256)*8];

    const int fr = l & 15;
    const int fk = (l >> 4) * 8;

    for (int kc = 0; kc < K_DIM; kc += 32){
        __syncthreads();
        GLD16(gA0 + kc, lA0);
        GLD16(gA1 + kc, lA1);
        GLD16(gB0 + kc, lB0);
        GLD16(gB1 + kc, lB1);
        __syncthreads();
        short8 af[4], bfr[4];
        #pragma unroll
        for (int i = 0; i < 4; i++)
            af[i] = *(const short8*)&As[(wm + i*16 + fr)*32 + fk];
        #pragma unroll
        for (int jj = 0; jj < 4; jj++)
            bfr[jj] = *(const short8*)&Bs[(wn + jj*16 + fr)*32 + fk];
        #pragma unroll
        for (int i = 0; i < 4; i++)
            #pragma unroll
            for (int jj = 0; jj < 4; jj++)
                acc[i][jj] = __builtin_amdgcn_mfma_f32_16x16x32_bf16(af[i], bfr[jj], acc[i][jj], 0, 0, 0);
    }

    const int ntile = blockIdx.x;
    if (ntile < 24){
        const int crow0 = rowBase + wm + (l >> 4) * 4;
        const int ccol0 = colBase + wn + (l & 15);
        #pragma unroll
        for (int i = 0; i < 4; i++)
            #pragma unroll
            for (int jj = 0; jj < 4; jj++)
                #pragma unroll
                for (int r = 0; r < 4; r++)
                    C[(size_t)(crow0 + i*16 + r) * NP_COLS + (ccol0 + jj*16)] = acc[i][jj][r];
    } else {
        const int isBeta = (ntile >= 32) ? 1 : 0;
        const float* bias = isBeta ? b_beta : b_alpha;
        const int gcol0 = colBase + wn - (isBeta ? 4096 : 3072);   // 0..960
        const int hh = gcol0 >> 6;                                  // head 0..15
        float bj[4];
        #pragma unroll
        for (int jj = 0; jj < 4; jj++) bj[jj] = bias[gcol0 + jj*16 + (l & 15)];
        #pragma unroll
        for (int i = 0; i < 4; i++){
            #pragma unroll
            for (int r = 0; r < 4; r++){
                float sum = 0.f;
                #pragma unroll
                for (int jj = 0; jj < 4; jj++) sum += sigf(acc[i][jj][r] + bj[jj]);
                sum = red16(sum);
                if ((l & 15) == 0){
                    const int row = rowBase + wm + i*16 + (l >> 4)*4 + r;
                    const int t = row >> 3, bb = row & 7;
                    G[((size_t)(bb*16 + hh)*1024 + t)*2 + isBeta] = sum * (1.f/64.f);
                }
            }
        }
    }
}

// ---------------- postpass: normalize q/k, pack scan stream ----------------
// KQV record per (bh, t): 512 B = [64 bf16 khat][64 bf16 qhat][64 fp32 v]
__global__ __launch_bounds__(256) void postpass(const float* __restrict__ C,
                                                unsigned char* __restrict__ KQV){
    const int i = blockIdx.x;           // row 0..8191; t=i>>3, b=i&7
    const int tid = threadIdx.x;
    const int h = tid >> 4;
    const int j = tid & 15;
    const int e = j * 4;
    const float* base = C + (size_t)i * NP_COLS;

    float4 q4 = *(const float4*)(base +        h*64 + e);
    float4 k4 = *(const float4*)(base + 1024 + h*64 + e);
    float4 v4 = *(const float4*)(base + 2048 + h*64 + e);

    float qs = q4.x*q4.x + q4.y*q4.y + q4.z*q4.z + q4.w*q4.w;
    float ks = k4.x*k4.x + k4.y*k4.y + k4.z*k4.z + k4.w*k4.w;
    qs = red16(qs);
    ks = red16(ks);
    const float rq = 1.f / fmaxf(sqrtf(qs), 1e-12f);
    const float rk = 1.f / fmaxf(sqrtf(ks), 1e-12f);

    const size_t rec = (size_t)((i & 7)*16 + h) * 1024 + (i >> 3);
    unsigned char* rp = KQV + rec * 512;
    ushort4 kp, qp;
    kp.x = f2bf(k4.x*rk); kp.y = f2bf(k4.y*rk); kp.z = f2bf(k4.z*rk); kp.w = f2bf(k4.w*rk);
    qp.x = f2bf(q4.x*rq); qp.y = f2bf(q4.y*rq); qp.z = f2bf(q4.z*rq); qp.w = f2bf(q4.w*rq);
    ((ushort4*)rp)[j]             = kp;          // bytes [0,128)
    ((ushort4*)(rp + 128))[j]     = qp;          // bytes [128,256)
    ((float4*)(rp + 256))[j]      = v4;          // bytes [256,512)
}

// ---------------- sequential scan ----------------
// 512 blocks: bh*4+quarter; 16 rows/block, 16 lanes x 4 state elems per row.
// 2 blocks/CU -> 2 waves/SIMD for latency hiding.
__global__ __launch_bounds__(256) void scan_kernel(const unsigned char* __restrict__ KQV,
        const float* __restrict__ G,
        const float* __restrict__ S0, float* __restrict__ out){
    const int bh      = blockIdx.x >> 2;   // 0..127
    const int quarter = blockIdx.x & 3;
    const int b = bh >> 4;
    const int h = bh & 15;
    const int tid = threadIdx.x;
    const int jj  = tid & 15;              // element group within row
    const int lr  = tid >> 4;              // 0..15 row within quarter
    const int d   = quarter*16 + lr;
    const int wv = tid >> 6;
    const int lane = tid & 63;

    __shared__ unsigned char sRec[2][CT*512];
    __shared__ float sG[2][CT*2];

    const unsigned char* gRec = KQV + (size_t)bh * (1024*512);
    const unsigned char* gG   = (const unsigned char*)G + (size_t)bh * (1024*8);

    // stage chunk 0
    {
        const unsigned char* src = gRec + wv*4096 + lane*16;
        unsigned char* dst = &sRec[0][0] + wv*4096 + lane*16;
        #pragma unroll
        for (int it = 0; it < 4; it++) GLD16(src + it*1024, dst + it*1024);
        if (wv == 0) GLD4(gG + lane*4, (unsigned char*)&sG[0][0] + lane*4);
    }

    float s[4];
    {
        const float* s0p = S0 + ((size_t)bh*64 + d)*64 + jj*4;
        #pragma unroll
        for (int e2 = 0; e2 < 4; e2++) s[e2] = s0p[e2];
    }

    for (int c = 0; c < NCHUNK; ++c){
        __syncthreads();                        // chunk c ready (barrier drains vmcnt)
        const int buf = c & 1;
        if (c + 1 < NCHUNK){                    // prefetch chunk c+1 into other buffer
            const unsigned char* src = gRec + (size_t)(c+1)*(CT*512) + wv*4096 + lane*16;
            unsigned char* dst = &sRec[buf^1][0] + wv*4096 + lane*16;
            #pragma unroll
            for (int it = 0; it < 4; it++) GLD16(src + it*1024, dst + it*1024);
            if (wv == 0) GLD4(gG + (size_t)(c+1)*(CT*8) + lane*4,
                              (unsigned char*)&sG[buf^1][0] + lane*4);
        }
        #pragma unroll
        for (int tl = 0; tl < CT; ++tl){
            const unsigned char* rec = &sRec[buf][tl*512];
            const uint2 kw = *(const uint2*)(rec + (jj<<3));
            const uint2 qw = *(const uint2*)(rec + 128 + (jj<<3));
            const float vd = *(const float*)(rec + 256 + (d<<2));
            const float2 g = *(const float2*)(&sG[buf][tl*2]);

            float kk[4];
            kk[0]=bflo(kw.x); kk[1]=bfhi(kw.x); kk[2]=bflo(kw.y); kk[3]=bfhi(kw.y);

            float sk = (s[0]*kk[0] + s[2]*kk[2]) + (s[1]*kk[1] + s[3]*kk[3]);
            sk = red16(sk);

            const float c1 = g.y * (vd - g.x * sk);
            #pragma unroll
            for (int e2 = 0; e2 < 4; e2++) s[e2] = g.x*s[e2] + c1*kk[e2];

            float qq[4];
            qq[0]=bflo(qw.x); qq[1]=bfhi(qw.x); qq[2]=bflo(qw.y); qq[3]=bfhi(qw.y);
            float o = (s[0]*qq[0] + s[2]*qq[2]) + (s[1]*qq[1] + s[3]*qq[3]);
            o = red16(o);

            if (jj == 0){
                const int t = c*CT + tl;
                out[(size_t)t*8192 + b*1024 + h*64 + d] = o;
            }
        }
    }

    // S_final
    float* sf = out + (size_t)8388608 + ((size_t)bh*64 + d)*64 + jj*4;
    #pragma unroll
    for (int e2 = 0; e2 < 4; e2++) sf[e2] = s[e2];
}

extern "C" void kernel_launch(void* const* d_in, const int* in_sizes, int n_in,
                              void* d_out, int out_size, void* d_ws, size_t ws_size,
                              hipStream_t stream){
    const float* x  = (const float*)d_in[0];
    const float* S0 = (const float*)d_in[1];
    const float* Wq = (const float*)d_in[2];
    const float* Wk = (const float*)d_in[3];
    const float* Wv = (const float*)d_in[4];
    const float* Wa = (const float*)d_in[5];
    const float* ba = (const float*)d_in[6];
    const float* Wb = (const float*)d_in[7];
    const float* bb = (const float*)d_in[8];
    float* out = (float*)d_out;

    char* ws = (char*)d_ws;
    unsigned short* Abf = (unsigned short*)ws;                    // 16,777,216 B
    unsigned short* Bbf = (unsigned short*)(ws + 16777216);       // 10,485,760 B
    float* Cm  = (float*)(ws + 27262976);                         // 100,663,296 B (8192x3072 fp32)
    unsigned char* KQV = (unsigned char*)(ws + 127926272);        // 67,108,864 B (128*1024*512)
    float* G   = (float*)(ws + 195035136);                        //  1,048,576 B -> end 196,083,712

    // conversions
    cvt_bf16<<<2048, 256, 0, stream>>>(x, Abf, (M_ROWS*K_DIM)/4);
    cvt_w<<<5120, 256, 0, stream>>>(Wq, Wk, Wv, Wa, Wb, Bbf);

    // fused projection GEMM (q/k/v -> Cm; alpha/beta -> G)
    dim3 gg(N_COLS/128, M_ROWS/128);   // 40 x 64
    gemm_bt<<<gg, 256, 0, stream>>>(Abf, Bbf, Cm, G, ba, bb);

    // normalize + pack scan stream
    postpass<<<M_ROWS, 256, 0, stream>>>(Cm, KQV);

    // recurrence
    scan_kernel<<<512, 256, 0, stream>>>(KQV, G, S0, out);
}

// Round 4
// 433.842 us; speedup vs baseline: 2.7193x; 1.0368x over previous
//
#include <hip/hip_runtime.h>
#include <hip/hip_bf16.h>
#include <math.h>

#define T_DIM 1024
#define B_DIM 8
#define D_DIM 1024
#define H_DIM 16
#define DH 64
#define M_ROWS 8192          // T*B
#define N_COLS 5120          // 5*D
#define K_DIM 1024
#define CT 32                // scan chunk (timesteps per LDS stage)
#define NCHUNK (T_DIM / CT)
#define REC 768              // bytes per (bh,t): [k fp32 x64][q fp32 x64][v fp32 x64]

typedef __attribute__((ext_vector_type(8))) short short8;
typedef __attribute__((ext_vector_type(4))) float floatx4;

static __device__ __forceinline__ unsigned short f2bf(float f){
    unsigned int u = __float_as_uint(f);
    u += 0x7fff + ((u >> 16) & 1);          // RNE
    return (unsigned short)(u >> 16);
}
static __device__ __forceinline__ float sigf(float x){
    return 1.f / (1.f + __expf(-x));
}

// DPP butterfly adds on VALU pipe: xor1=quad_perm[1,0,3,2]=0xB1,
// xor2=quad_perm[2,3,0,1]=0x4E, xor4=row_half_mirror=0x141, xor8=row_mirror=0x140
#define DPPADD(x, ctrl) ((x) + __int_as_float(__builtin_amdgcn_update_dpp(0, __float_as_int(x), (ctrl), 0xF, 0xF, true)))
static __device__ __forceinline__ float red16(float x){
    x = DPPADD(x, 0xB1); x = DPPADD(x, 0x4E); x = DPPADD(x, 0x141); x = DPPADD(x, 0x140); return x;
}
static __device__ __forceinline__ void red16x2(float& x, float& y){
    x = DPPADD(x, 0xB1);  y = DPPADD(y, 0xB1);
    x = DPPADD(x, 0x4E);  y = DPPADD(y, 0x4E);
    x = DPPADD(x, 0x141); y = DPPADD(y, 0x141);
    x = DPPADD(x, 0x140); y = DPPADD(y, 0x140);
}

// ---------------- fp32 -> bf16 conversion ----------------
__global__ void cvt_bf16(const float* __restrict__ src, unsigned short* __restrict__ dst, int n4){
    int i = blockIdx.x*blockDim.x + threadIdx.x;
    int stride = gridDim.x*blockDim.x;
    for (; i < n4; i += stride){
        float4 f = ((const float4*)src)[i];
        ushort4 o;
        o.x = f2bf(f.x); o.y = f2bf(f.y); o.z = f2bf(f.z); o.w = f2bf(f.w);
        ((ushort4*)dst)[i] = o;
    }
}

__global__ void cvt_w(const float* __restrict__ w0, const float* __restrict__ w1,
                      const float* __restrict__ w2, const float* __restrict__ w3,
                      const float* __restrict__ w4, unsigned short* __restrict__ dst){
    int i = blockIdx.x*blockDim.x + threadIdx.x;   // one float4 each; 5*262144 total
    int seg = i >> 18;
    int off = i & 262143;
    const float* src = (seg==0)?w0:(seg==1)?w1:(seg==2)?w2:(seg==3)?w3:w4;
    float4 f = ((const float4*)src)[off];
    ushort4 o;
    o.x = f2bf(f.x); o.y = f2bf(f.y); o.z = f2bf(f.z); o.w = f2bf(f.w);
    ((ushort4*)dst)[i] = o;
}

// ---------------- NT GEMM + fully fused epilogue ----------------
// n-tile 0..7: q -> l2-normalize rows -> KQV[rec][256..512)
// n-tile 8..15: k -> l2-normalize rows -> KQV[rec][0..256)
// n-tile 16..23: v -> KQV[rec][512..768)
// n-tile 24..31: alpha -> G[rec].x ; 32..39: beta -> G[rec].y
#define GLD16(g, l) __builtin_amdgcn_global_load_lds(                         \
    (const __attribute__((address_space(1))) void*)(g),                       \
    (__attribute__((address_space(3))) void*)(l), 16, 0, 0)

__global__ __launch_bounds__(256) void gemm_bt(const unsigned short* __restrict__ A,
                                               const unsigned short* __restrict__ B,
                                               unsigned char* __restrict__ KQV,
                                               float* __restrict__ G,
                                               const float* __restrict__ b_alpha,
                                               const float* __restrict__ b_beta){
    __shared__ unsigned short As[128*32];
    __shared__ unsigned short Bs[128*32];
    const int tid = threadIdx.x;
    const int rowBase = blockIdx.y * 128;
    const int colBase = blockIdx.x * 128;
    const int l  = tid & 63;
    const int wv = tid >> 6;
    const int wm = (wv >> 1) * 64;
    const int wn = (wv & 1) * 64;

    floatx4 acc[4][4] = {};

    const int r0 = tid >> 2;
    const int kj = (tid & 3) * 8;
    const unsigned short* gA0 = A + (size_t)(rowBase + r0)      * K_DIM + kj;
    const unsigned short* gA1 = A + (size_t)(rowBase + r0 + 64) * K_DIM + kj;
    const unsigned short* gB0 = B + (size_t)(colBase + r0)      * K_DIM + kj;
    const unsigned short* gB1 = B + (size_t)(colBase + r0 + 64) * K_DIM + kj;
    unsigned short* lA0 = &As[tid*8];
    unsigned short* lA1 = &As[(tid+256)*8];
    unsigned short* lB0 = &Bs[tid*8];
    unsigned short* lB1 = &Bs[(tid+256)*8];

    const int fr = l & 15;
    const int fk = (l >> 4) * 8;

    for (int kc = 0; kc < K_DIM; kc += 32){
        __syncthreads();
        GLD16(gA0 + kc, lA0);
        GLD16(gA1 + kc, lA1);
        GLD16(gB0 + kc, lB0);
        GLD16(gB1 + kc, lB1);
        __syncthreads();
        short8 af[4], bfr[4];
        #pragma unroll
        for (int i = 0; i < 4; i++)
            af[i] = *(const short8*)&As[(wm + i*16 + fr)*32 + fk];
        #pragma unroll
        for (int jj = 0; jj < 4; jj++)
            bfr[jj] = *(const short8*)&Bs[(wn + jj*16 + fr)*32 + fk];
        #pragma unroll
        for (int i = 0; i < 4; i++)
            #pragma unroll
            for (int jj = 0; jj < 4; jj++)
                acc[i][jj] = __builtin_amdgcn_mfma_f32_16x16x32_bf16(af[i], bfr[jj], acc[i][jj], 0, 0, 0);
    }

    const int ntile = blockIdx.x;
    const int l15 = l & 15;
    if (ntile < 24){
        const int gcol = colBase + wn;           // 0..3071
        const int seg  = gcol >> 10;             // 0=q, 1=k, 2=v
        const int h    = (gcol >> 6) & 15;
        if (seg < 2){
            const int segOff = (seg == 0) ? 256 : 0;
            #pragma unroll
            for (int i = 0; i < 4; i++){
                #pragma unroll
                for (int r = 0; r < 4; r++){
                    float ss = acc[i][0][r]*acc[i][0][r] + acc[i][1][r]*acc[i][1][r]
                             + acc[i][2][r]*acc[i][2][r] + acc[i][3][r]*acc[i][3][r];
                    ss = red16(ss);
                    const float rn = 1.f / fmaxf(sqrtf(ss), 1e-12f);
                    const int row = rowBase + wm + i*16 + (l >> 4)*4 + r;
                    const size_t rec = (size_t)((row & 7)*16 + h)*1024 + (row >> 3);
                    float* rp = (float*)(KQV + rec*REC + segOff);
                    #pragma unroll
                    for (int jj = 0; jj < 4; jj++)
                        rp[jj*16 + l15] = acc[i][jj][r] * rn;
                }
            }
        } else {
            #pragma unroll
            for (int i = 0; i < 4; i++){
                #pragma unroll
                for (int r = 0; r < 4; r++){
                    const int row = rowBase + wm + i*16 + (l >> 4)*4 + r;
                    const size_t rec = (size_t)((row & 7)*16 + h)*1024 + (row >> 3);
                    float* rp = (float*)(KQV + rec*REC + 512);
                    #pragma unroll
                    for (int jj = 0; jj < 4; jj++)
                        rp[jj*16 + l15] = acc[i][jj][r];
                }
            }
        }
    } else {
        const int isBeta = (ntile >= 32) ? 1 : 0;
        const float* bias = isBeta ? b_beta : b_alpha;
        const int gcol0 = colBase + wn - (isBeta ? 4096 : 3072);   // 0..960
        const int hh = gcol0 >> 6;                                  // head 0..15
        float bj[4];
        #pragma unroll
        for (int jj = 0; jj < 4; jj++) bj[jj] = bias[gcol0 + jj*16 + l15];
        #pragma unroll
        for (int i = 0; i < 4; i++){
            #pragma unroll
            for (int r = 0; r < 4; r++){
                float sum = 0.f;
                #pragma unroll
                for (int jj = 0; jj < 4; jj++) sum += sigf(acc[i][jj][r] + bj[jj]);
                sum = red16(sum);
                if (l15 == 0){
                    const int row = rowBase + wm + i*16 + (l >> 4)*4 + r;
                    const int t = row >> 3, bb = row & 7;
                    G[(((size_t)(bb*16 + hh)*1024 + t))*4 + isBeta] = sum * (1.f/64.f);
                }
            }
        }
    }
}

// ---------------- kq precompute: G[bh][t].z = dot(khat, qhat) ----------------
__global__ __launch_bounds__(256) void kq_kernel(const unsigned char* __restrict__ KQV,
                                                 float* __restrict__ G){
    const int bh = blockIdx.x >> 2;
    const int tq = blockIdx.x & 3;
    const int g  = threadIdx.x >> 4;
    const int j  = threadIdx.x & 15;
    #pragma unroll 4
    for (int it = 0; it < 16; ++it){
        const int t = tq*256 + it*16 + g;
        const float* rp = (const float*)(KQV + ((size_t)bh*1024 + t)*REC);
        float4 k4 = *(const float4*)(rp + j*4);
        float4 q4 = *(const float4*)(rp + 64 + j*4);
        float s = k4.x*q4.x + k4.y*q4.y + k4.z*q4.z + k4.w*q4.w;
        s = red16(s);
        if (j == 0) G[(((size_t)bh*1024 + t))*4 + 2] = s;
    }
}

// ---------------- sequential scan ----------------
// 512 blocks: bh*4+quarter; 16 rows/block, 16 lanes x 4 state elems per row.
// Restructured step: sk and sq reduced in parallel; out uses precomputed kq.
__global__ __launch_bounds__(256) void scan_kernel(const unsigned char* __restrict__ KQV,
        const float* __restrict__ G,
        const float* __restrict__ S0, float* __restrict__ out){
    const int bh      = blockIdx.x >> 2;   // 0..127
    const int quarter = blockIdx.x & 3;
    const int b = bh >> 4;
    const int h = bh & 15;
    const int tid = threadIdx.x;
    const int jj  = tid & 15;              // element group within row
    const int lr  = tid >> 4;              // 0..15 row within quarter
    const int d   = quarter*16 + lr;

    __shared__ unsigned char sRec[2][CT*REC];    // 24576 B each
    __shared__ float4 sG[2][CT];

    const unsigned char* gRec = KQV + (size_t)bh * (1024*REC);
    const unsigned char* gG   = (const unsigned char*)G + (size_t)bh * (1024*16);

    // stage chunk 0
    {
        const unsigned char* src = gRec + tid*16;
        unsigned char* dst = &sRec[0][0] + tid*16;
        #pragma unroll
        for (int it = 0; it < 6; it++) GLD16(src + it*4096, dst + it*4096);
        if (tid < 32) GLD16(gG + tid*16, (unsigned char*)&sG[0][0] + tid*16);
    }

    float s[4];
    {
        const float* s0p = S0 + ((size_t)bh*64 + d)*64 + jj*4;
        float4 s4 = *(const float4*)s0p;
        s[0]=s4.x; s[1]=s4.y; s[2]=s4.z; s[3]=s4.w;
    }

    for (int c = 0; c < NCHUNK; ++c){
        __syncthreads();                        // chunk c ready
        const int buf = c & 1;
        if (c + 1 < NCHUNK){                    // prefetch chunk c+1
            const unsigned char* src = gRec + (size_t)(c+1)*(CT*REC) + tid*16;
            unsigned char* dst = &sRec[buf^1][0] + tid*16;
            #pragma unroll
            for (int it = 0; it < 6; it++) GLD16(src + it*4096, dst + it*4096);
            if (tid < 32) GLD16(gG + (size_t)(c+1)*(CT*16) + tid*16,
                                (unsigned char*)&sG[buf^1][0] + tid*16);
        }
        #pragma unroll
        for (int tl = 0; tl < CT; ++tl){
            const unsigned char* rec = &sRec[buf][tl*REC];
            const float4 k4 = *(const float4*)(rec + (jj<<4));
            const float4 q4 = *(const float4*)(rec + 256 + (jj<<4));
            const float vd  = *(const float*)(rec + 512 + (d<<2));
            const float4 g  = sG[buf][tl];      // a, be, kq, -

            float sk = (s[0]*k4.x + s[2]*k4.z) + (s[1]*k4.y + s[3]*k4.w);
            float sq = (s[0]*q4.x + s[2]*q4.z) + (s[1]*q4.y + s[3]*q4.w);
            red16x2(sk, sq);

            const float c1 = g.y * (vd - g.x * sk);
            const float o  = g.x * sq + c1 * g.z;

            s[0] = g.x*s[0] + c1*k4.x;
            s[1] = g.x*s[1] + c1*k4.y;
            s[2] = g.x*s[2] + c1*k4.z;
            s[3] = g.x*s[3] + c1*k4.w;

            if (jj == 0){
                const int t = c*CT + tl;
                out[(size_t)t*8192 + b*1024 + h*64 + d] = o;
            }
        }
    }

    // S_final
    float* sf = out + (size_t)8388608 + ((size_t)bh*64 + d)*64 + jj*4;
    float4 s4; s4.x=s[0]; s4.y=s[1]; s4.z=s[2]; s4.w=s[3];
    *(float4*)sf = s4;
}

extern "C" void kernel_launch(void* const* d_in, const int* in_sizes, int n_in,
                              void* d_out, int out_size, void* d_ws, size_t ws_size,
                              hipStream_t stream){
    const float* x  = (const float*)d_in[0];
    const float* S0 = (const float*)d_in[1];
    const float* Wq = (const float*)d_in[2];
    const float* Wk = (const float*)d_in[3];
    const float* Wv = (const float*)d_in[4];
    const float* Wa = (const float*)d_in[5];
    const float* ba = (const float*)d_in[6];
    const float* Wb = (const float*)d_in[7];
    const float* bb = (const float*)d_in[8];
    float* out = (float*)d_out;

    char* ws = (char*)d_ws;
    unsigned short* Abf = (unsigned short*)ws;                    // 16,777,216 B
    unsigned short* Bbf = (unsigned short*)(ws + 16777216);       // 10,485,760 B
    unsigned char* KQV = (unsigned char*)(ws + 27262976);         // 100,663,296 B (128*1024*768)
    float* G   = (float*)(ws + 127926272);                        //  2,097,152 B -> end 130,023,424

    // conversions
    cvt_bf16<<<2048, 256, 0, stream>>>(x, Abf, (M_ROWS*K_DIM)/4);
    cvt_w<<<5120, 256, 0, stream>>>(Wq, Wk, Wv, Wa, Wb, Bbf);

    // fused projection GEMM (khat/qhat/v -> KQV; alpha/beta -> G.xy)
    dim3 gg(N_COLS/128, M_ROWS/128);   // 40 x 64
    gemm_bt<<<gg, 256, 0, stream>>>(Abf, Bbf, KQV, G, ba, bb);

    // kq = dot(khat, qhat) -> G.z
    kq_kernel<<<512, 256, 0, stream>>>(KQV, G);

    // recurrence
    scan_kernel<<<512, 256, 0, stream>>>(KQV, G, S0, out);
}